// Round 4
// baseline (59.942 us; speedup 1.0000x reference)
//
#include <hip/hip_runtime.h>

// Problem constants (from reference): B=16, S=4096, H=1024, NSEG=512
constexpr int B    = 16;
constexpr int S    = 4096;
constexpr int H    = 1024;
constexpr int NSEG = 512;

// Native clang vector type — __builtin_nontemporal_load/store require a
// pointer to scalar or native vector (HIP_vector_type float4 is rejected).
typedef float floatx4 __attribute__((ext_vector_type(4)));

// ---------------------------------------------------------------------------
// Kernel 1: segment-boundary precompute.
// output_mask is sorted non-decreasing per batch row, so segment `seg`
// occupies the contiguous token range [bounds[seg], bounds[seg+1]).
// One thread per token: where the id changes between i-1 and i, all segments
// in (prev, cur] start at i. Thread S-1 additionally closes the tail.
// bounds layout: [B][NSEG+1] ints in d_ws (16*513*4 = 32,832 B).
// ---------------------------------------------------------------------------
__global__ __launch_bounds__(256) void seg_bounds_kernel(
    const int* __restrict__ mask,   // [B, S] sorted per row
    int*       __restrict__ bounds) // [B, NSEG+1]
{
    const int idx = blockIdx.x * blockDim.x + threadIdx.x;  // 0 .. B*S-1
    const int b = idx >> 12;          // / S (S = 4096)
    const int i = idx & (S - 1);

    const int* row  = mask + b * S;
    int*       brow = bounds + b * (NSEG + 1);

    int cur  = row[i];
    int prev = (i == 0) ? -1 : row[i - 1];

    // clamp to valid segment-id space (ids < 0 are "dropped" tokens)
    if (cur  > NSEG - 1) cur  = NSEG - 1;
    if (prev < -1)       prev = -1;

    for (int s = prev + 1; s <= cur; ++s) brow[s] = i;
    if (i == S - 1) {
        for (int s = (cur < 0 ? 0 : cur + 1); s <= NSEG; ++s) brow[s] = S;
    }
}

// ---------------------------------------------------------------------------
// Kernel 2: dense mean over the contiguous token range of each (b, seg).
// One block per output row. 256 threads * floatx4 = full 1024-col row per
// token (fully coalesced, 16 B/lane). 8x unrolled with 4 accumulators so
// 8 float4 HBM loads are in flight per thread. Non-temporal loads/stores:
// hs is read exactly once and out written once -> no cache allocation.
// ---------------------------------------------------------------------------
__global__ __launch_bounds__(256) void seg_mean_kernel(
    const float* __restrict__ hs,     // [B, S, H]
    const int*   __restrict__ bounds, // [B, NSEG+1]
    float*       __restrict__ out)    // [B*NSEG, H]
{
    const int gid = blockIdx.x;          // 0 .. B*NSEG-1
    const int b   = gid >> 9;            // / NSEG
    const int seg = gid & (NSEG - 1);

    const int* brow  = bounds + b * (NSEG + 1);
    const int  start = brow[seg];        // broadcast load (L2-hit, cached)
    const int  end   = brow[seg + 1];
    const int  cnt   = end - start;

    const int col = threadIdx.x << 2;    // 4 columns per thread

    const floatx4* base =
        reinterpret_cast<const floatx4*>(hs + ((size_t)b * S + (size_t)start) * H + col);
    const int strideV = H / 4;           // floatx4 elements per token row

    floatx4 a0 = (floatx4)0.f;
    floatx4 a1 = (floatx4)0.f;
    floatx4 a2 = (floatx4)0.f;
    floatx4 a3 = (floatx4)0.f;

    int t = 0;
    for (; t + 8 <= cnt; t += 8) {
        floatx4 v0 = __builtin_nontemporal_load(base + (size_t)(t + 0) * strideV);
        floatx4 v1 = __builtin_nontemporal_load(base + (size_t)(t + 1) * strideV);
        floatx4 v2 = __builtin_nontemporal_load(base + (size_t)(t + 2) * strideV);
        floatx4 v3 = __builtin_nontemporal_load(base + (size_t)(t + 3) * strideV);
        floatx4 v4 = __builtin_nontemporal_load(base + (size_t)(t + 4) * strideV);
        floatx4 v5 = __builtin_nontemporal_load(base + (size_t)(t + 5) * strideV);
        floatx4 v6 = __builtin_nontemporal_load(base + (size_t)(t + 6) * strideV);
        floatx4 v7 = __builtin_nontemporal_load(base + (size_t)(t + 7) * strideV);
        a0 += v0; a1 += v1; a2 += v2; a3 += v3;
        a0 += v4; a1 += v5; a2 += v6; a3 += v7;
    }
    for (; t < cnt; ++t) {
        floatx4 v = __builtin_nontemporal_load(base + (size_t)t * strideV);
        a0 += v;
    }

    a0 += a1; a2 += a3; a0 += a2;

    const float inv = (cnt > 0) ? (1.0f / (float)cnt) : 0.0f;
    a0 *= inv;

    __builtin_nontemporal_store(a0,
        reinterpret_cast<floatx4*>(out + (size_t)gid * H + col));
}

extern "C" void kernel_launch(void* const* d_in, const int* in_sizes, int n_in,
                              void* d_out, int out_size, void* d_ws, size_t ws_size,
                              hipStream_t stream) {
    const float* hs   = (const float*)d_in[0];  // hidden_states [B,S,H] f32
    const int*   mask = (const int*)  d_in[1];  // output_mask  [B,S] i32

    float* out    = (float*)d_out;              // [B*NSEG, H] f32
    int*   bounds = (int*)d_ws;                 // [B, NSEG+1] i32 scratch

    seg_bounds_kernel<<<dim3((B * S) / 256), dim3(256), 0, stream>>>(mask, bounds);
    seg_mean_kernel <<<dim3(B * NSEG),       dim3(256), 0, stream>>>(hs, bounds, out);
}

// Round 5
// 50.697 us; speedup vs baseline: 1.1824x; 1.1824x over previous
//
#include <hip/hip_runtime.h>

// Problem constants (from reference): B=16, S=4096, H=1024, NSEG=512
constexpr int B    = 16;
constexpr int S    = 4096;
constexpr int H    = 1024;
constexpr int NSEG = 512;

// ---------------------------------------------------------------------------
// Fused kernel: one block per output row (b, seg).
//
// Bounds: output_mask is sorted non-decreasing per batch row, so segment
// `seg` occupies the contiguous token range
// [lower_bound(seg), lower_bound(seg+1)). Instead of a separate bounds
// kernel (extra launch) or a serial binary search (24 dependent L2 probes),
// use a wave-parallel 64-ary search: 64 lanes probe chunk-ends at stride 64,
// __ballot + ffs picks the chunk, then 64 lanes probe within the chunk.
// 2 dependent rounds (~400-800 cyc, L2-hit) instead of ~12 serial probes.
// Wave 0 searches lower_bound(seg), wave 1 searches lower_bound(seg+1).
//
// Accumulation (R2's proven loop): 256 threads * float4 = full 1024-col row
// per token, fully coalesced. 4x unrolled, two accumulators, plain loads.
// ---------------------------------------------------------------------------
__global__ __launch_bounds__(256) void seg_mean_fused_kernel(
    const float* __restrict__ hs,    // [B, S, H]
    const int*   __restrict__ mask,  // [B, S] sorted per row
    float*       __restrict__ out)   // [B*NSEG, H]
{
    const int gid = blockIdx.x;          // 0 .. B*NSEG-1
    const int b   = gid >> 9;            // / NSEG
    const int seg = gid & (NSEG - 1);

    __shared__ int s_bounds[2];

    const int wave = threadIdx.x >> 6;
    const int lane = threadIdx.x & 63;

    if (wave < 2) {
        const int  x   = seg + wave;     // wave0: lower_bound(seg), wave1: lower_bound(seg+1)
        const int* row = mask + b * S;

        // Level 1: lane l probes the last element of 64-chunk l.
        int p1 = row[lane * 64 + 63];
        unsigned long long m1 = __ballot(p1 >= x);
        int bound;
        if (m1 == 0ull) {
            bound = S;                   // all elements < x
        } else {
            int c = __ffsll((unsigned long long)m1) - 1;   // chunk containing bound
            // Level 2: lane l probes row[c*64 + l].
            int p2 = row[c * 64 + lane];
            unsigned long long m2 = __ballot(p2 >= x);
            bound = c * 64 + (__ffsll((unsigned long long)m2) - 1);
        }
        if (lane == 0) s_bounds[wave] = bound;
    }
    __syncthreads();

    const int start = s_bounds[0];
    const int cnt   = s_bounds[1] - start;

    const int col = threadIdx.x << 2;    // 4 columns per thread

    const float* base = hs + ((size_t)b * S + (size_t)start) * H + col;

    float4 a0 = make_float4(0.f, 0.f, 0.f, 0.f);
    float4 a1 = make_float4(0.f, 0.f, 0.f, 0.f);

    int t = 0;
    for (; t + 4 <= cnt; t += 4) {
        float4 v0 = *reinterpret_cast<const float4*>(base + (size_t)(t + 0) * H);
        float4 v1 = *reinterpret_cast<const float4*>(base + (size_t)(t + 1) * H);
        float4 v2 = *reinterpret_cast<const float4*>(base + (size_t)(t + 2) * H);
        float4 v3 = *reinterpret_cast<const float4*>(base + (size_t)(t + 3) * H);
        a0.x += v0.x; a0.y += v0.y; a0.z += v0.z; a0.w += v0.w;
        a1.x += v1.x; a1.y += v1.y; a1.z += v1.z; a1.w += v1.w;
        a0.x += v2.x; a0.y += v2.y; a0.z += v2.z; a0.w += v2.w;
        a1.x += v3.x; a1.y += v3.y; a1.z += v3.z; a1.w += v3.w;
    }
    for (; t < cnt; ++t) {
        float4 v = *reinterpret_cast<const float4*>(base + (size_t)t * H);
        a0.x += v.x; a0.y += v.y; a0.z += v.z; a0.w += v.w;
    }

    a0.x += a1.x; a0.y += a1.y; a0.z += a1.z; a0.w += a1.w;

    const float inv = (cnt > 0) ? (1.0f / (float)cnt) : 0.0f;
    a0.x *= inv; a0.y *= inv; a0.z *= inv; a0.w *= inv;

    *reinterpret_cast<float4*>(out + (size_t)gid * H + col) = a0;
}

extern "C" void kernel_launch(void* const* d_in, const int* in_sizes, int n_in,
                              void* d_out, int out_size, void* d_ws, size_t ws_size,
                              hipStream_t stream) {
    const float* hs   = (const float*)d_in[0];  // hidden_states [B,S,H] f32
    const int*   mask = (const int*)  d_in[1];  // output_mask  [B,S] i32

    float* out = (float*)d_out;                 // [B*NSEG, H] f32

    seg_mean_fused_kernel<<<dim3(B * NSEG), dim3(256), 0, stream>>>(hs, mask, out);
}